// Round 1
// 55.768 us; speedup vs baseline: 1.0883x; 1.0883x over previous
//
#include <hip/hip_runtime.h>

// 6-qubit RY-only circuit, fully factorized:
//   state after block1      = v(x) (x) e0            (product state, 8 values)
//   middle (x-independent)  = lane-diagonal reg-space op:  st[l][r] = W[l][r]*v[l]
//                             (r=7 column: CCC-Y -> +/- W7[l^7]*v[l^7]; phase i drops in |.|^2)
//   block2+entangle012      = (A*G(x)) on lane space; output needs only rows 0,7:
//                             R = A2 * (g0 (x) g1 (x) g2),  A2 = A[{0,7},:]  (2x8, x-indep)
//   out = 2*(||R1 . st||^2 - ||R0 . st||^2)  contracted per reg column.
// W (8x8, 64 floats) and A2 (2x8) depend only on p -> built once per block by
// threads 0..7 (W rows) and 64,65 (A2 rows, transposed-gate back-substitution),
// overlapping with every thread's own sin/cos + v(x) work.
// Per-element cost: 12 transcendentals + ~300 VALU on ONE thread (was 8 lanes x ~480).

template <int TB, int CB>  // RY on reg/lane bit TB, optional control bit CB (left-mul)
__device__ __forceinline__ void ryv(float* m, float c, float s) {
#pragma unroll
    for (int r = 0; r < 8; ++r) {
        if (r & TB) continue;
        if (CB && !(r & CB)) continue;
        float a0 = m[r], a1 = m[r + TB];
        m[r]      = fmaf(c, a0, -(s * a1));
        m[r + TB] = fmaf(s, a0, c * a1);
    }
}

template <int B>  // right-multiply row-vector M (1x8) by RY acting on column-bit B
__device__ __forceinline__ void rmul(float* M, float c, float s) {
    // (M*g): new_j = c*Mj + s*Mk ; new_k = c*Mk - s*Mj   (k = j+B)
#pragma unroll
    for (int j = 0; j < 8; ++j) {
        if (j & B) continue;
        float a = M[j], b = M[j + B];
        M[j]     = fmaf(c, a, s * b);
        M[j + B] = fmaf(c, b, -(s * a));
    }
}

__global__ __launch_bounds__(256) void pnn_kernel(const float* __restrict__ x,
                                                  const float* __restrict__ p,
                                                  float* __restrict__ out,
                                                  int n) {
    // cs table (identical layout to the verified previous kernel):
    //  [0..7]   fused q3-block (p6+0.5 + lane-controlled p3..p5), per lane
    //  [8..15]  fused q4-block, [16..23] fused q5-block
    //  [24..32] entangle q3q4q5: p15..p23
    //  [33..41] entangle q0q1q2: p27..p35
    __shared__ float2 cs_tab[42];
    __shared__ __align__(16) float Wl[8][8];   // Wl[l][r]; col 7 pre-signed (-1)^popc(l)
    __shared__ __align__(16) float A2r[2][8];  // rows 0 (l=0 -> p000) and 1 (l=7 -> p111) of A

    int t = threadIdx.x;
    if (t < 42) {
        float th;
        if (t < 24) {
            int tgt = t >> 3, ln = t & 7;
            int base = 3 + 4 * tgt;           // p[base..base+2] controlled, p[base+3] plain
            th = p[base + 3] + 0.5f;
            if (ln & 1) th += p[base];        // ctrl q2
            if (ln & 2) th += p[base + 1];    // ctrl q1
            if (ln & 4) th += p[base + 2];    // ctrl q0
        } else if (t < 33) {
            th = p[t - 9];                    // p15..p23
        } else {
            th = p[t - 6];                    // p27..p35
        }
        float h = th * 0.5f;
        cs_tab[t] = make_float2(__cosf(h), __sinf(h));
    }
    __syncthreads();

    int e = blockIdx.x * blockDim.x + t;
    bool live = (e < n);
    float xv = x[live ? e : 0];

    // --- per-element half-angles (block1 -> v, block2 -> G); uniform p-> scalar loads ---
    float h0 = fmaf(1.5f, xv, 0.5f * p[0]);           // (3x + p0)/2
    float h1 = fmaf(4.5f, xv, 0.5f * p[1]);           // (9x + p1)/2
    float h2 = fmaf(0.5f, xv, 0.5f * p[2]);           // ( x + p2)/2
    float h3 = fmaf(3.5f, xv, 0.5f * p[24] - 0.25f);  // (7x + p24 - 0.5)/2
    float h4 = fmaf(8.5f, xv, 0.5f * p[25] - 0.25f);  // (17x + p25 - 0.5)/2
    float h5 = fmaf(0.5f, xv, 0.5f * p[26] - 0.25f);  // ( x + p26 - 0.5)/2
    float c0 = __cosf(h0), s0 = __sinf(h0);
    float c1 = __cosf(h1), s1 = __sinf(h1);
    float c2 = __cosf(h2), s2 = __sinf(h2);
    float gc0 = __cosf(h3), gs0 = __sinf(h3);
    float gc1 = __cosf(h4), gs1 = __sinf(h4);
    float gc2 = __cosf(h5), gs2 = __sinf(h5);

    // v(x): product state over lane bits (q0->4, q1->2, q2->1)
    float q00 = c1 * c2, q01 = c1 * s2, q10 = s1 * c2, q11 = s1 * s2;
    float v[8];
    v[0] = c0 * q00; v[1] = c0 * q01; v[2] = c0 * q10; v[3] = c0 * q11;
    v[4] = s0 * q00; v[5] = s0 * q01; v[6] = s0 * q10; v[7] = s0 * q11;

    // --- prologue: wave0 threads 0..7 build W rows; wave1 threads 64,65 build A2 rows ---
    if (t < 8) {
        // m = (middle reg-space op for lane t) applied to e0; reg bits q3->4,q4->2,q5->1
        float m[8] = {1.f, 0.f, 0.f, 0.f, 0.f, 0.f, 0.f, 0.f};
        float2 G;
        G = cs_tab[t];      ryv<4, 0>(m, G.x, G.y);   // fused q3 block
        G = cs_tab[8 + t];  ryv<2, 0>(m, G.x, G.y);   // fused q4 block
        G = cs_tab[16 + t]; ryv<1, 0>(m, G.x, G.y);   // fused q5 block
        G = cs_tab[24]; ryv<2, 4>(m, G.x, G.y);       // p15: t4 c3
        G = cs_tab[25]; ryv<1, 4>(m, G.x, G.y);       // p16: t5 c3
        G = cs_tab[26]; ryv<4, 2>(m, G.x, G.y);       // p17: t3 c4
        G = cs_tab[27]; ryv<1, 2>(m, G.x, G.y);       // p18: t5 c4
        G = cs_tab[28]; ryv<4, 1>(m, G.x, G.y);       // p19: t3 c5
        G = cs_tab[29]; ryv<2, 1>(m, G.x, G.y);       // p20: t4 c5
        G = cs_tab[30]; ryv<4, 0>(m, G.x, G.y);       // p21
        G = cs_tab[31]; ryv<2, 0>(m, G.x, G.y);       // p22
        G = cs_tab[32]; ryv<1, 0>(m, G.x, G.y);       // p23
        float sgn = (__popc(t) & 1) ? -1.f : 1.f;     // CCC-Y sign, folded into col 7
#pragma unroll
        for (int r = 0; r < 7; ++r) Wl[t][r] = m[r];
        Wl[t][7] = sgn * m[7];
    }
    if (t == 64 || t == 65) {
        // row l of A via A^T e_l: transposed (s -> -s) entangle-012 gates in REVERSE order
        float w[8] = {0.f, 0.f, 0.f, 0.f, 0.f, 0.f, 0.f, 0.f};
        w[(t == 64) ? 0 : 7] = 1.f;
        float2 G;
        G = cs_tab[41]; ryv<1, 0>(w, G.x, -G.y);      // p35: t q2
        G = cs_tab[40]; ryv<2, 0>(w, G.x, -G.y);      // p34: t q1
        G = cs_tab[39]; ryv<4, 0>(w, G.x, -G.y);      // p33: t q0
        G = cs_tab[38]; ryv<2, 1>(w, G.x, -G.y);      // p32: t q1 c q2
        G = cs_tab[37]; ryv<4, 1>(w, G.x, -G.y);      // p31: t q0 c q2
        G = cs_tab[36]; ryv<1, 2>(w, G.x, -G.y);      // p30: t q2 c q1
        G = cs_tab[35]; ryv<4, 2>(w, G.x, -G.y);      // p29: t q0 c q1
        G = cs_tab[34]; ryv<1, 4>(w, G.x, -G.y);      // p28: t q2 c q0
        G = cs_tab[33]; ryv<2, 4>(w, G.x, -G.y);      // p27: t q1 c q0
#pragma unroll
        for (int l = 0; l < 8; ++l) A2r[t - 64][l] = w[l];
    }
    __syncthreads();

    // --- load W (16x ds_read_b128 broadcast) and A2 rows into registers ---
    float W[8][8];
#pragma unroll
    for (int l = 0; l < 8; ++l) {
        float4 lo = *(const float4*)&Wl[l][0];
        float4 hi = *(const float4*)&Wl[l][4];
        W[l][0] = lo.x; W[l][1] = lo.y; W[l][2] = lo.z; W[l][3] = lo.w;
        W[l][4] = hi.x; W[l][5] = hi.y; W[l][6] = hi.z; W[l][7] = hi.w;
    }
    float M0[8], M1[8];
    {
        float4 lo = *(const float4*)&A2r[0][0];
        float4 hi = *(const float4*)&A2r[0][4];
        M0[0] = lo.x; M0[1] = lo.y; M0[2] = lo.z; M0[3] = lo.w;
        M0[4] = hi.x; M0[5] = hi.y; M0[6] = hi.z; M0[7] = hi.w;
        lo = *(const float4*)&A2r[1][0];
        hi = *(const float4*)&A2r[1][4];
        M1[0] = lo.x; M1[1] = lo.y; M1[2] = lo.z; M1[3] = lo.w;
        M1[4] = hi.x; M1[5] = hi.y; M1[6] = hi.z; M1[7] = hi.w;
    }

    // --- R = A2 * (g0 (x) g1 (x) g2)   (block2, x-dependent, commuting targets) ---
    rmul<4>(M0, gc0, gs0); rmul<4>(M1, gc0, gs0);
    rmul<2>(M0, gc1, gs1); rmul<2>(M1, gc1, gs1);
    rmul<1>(M0, gc2, gs2); rmul<1>(M1, gc2, gs2);

    // --- contraction: amp_i[r] = sum_l (M_i[l]*v[l]) * W[l][r]  (r<7)
    //                 amp_i[7] = sum_l  M_i[l] * (W[l^7][7]*v[l^7])   (global sign dropped)
    float u0[8], u1[8], z[8];
#pragma unroll
    for (int l = 0; l < 8; ++l) {
        u0[l] = M0[l] * v[l];
        u1[l] = M1[l] * v[l];
        z[l]  = W[l ^ 7][7] * v[l ^ 7];
    }
    float p000 = 0.f, p111 = 0.f;
#pragma unroll
    for (int r = 0; r < 7; ++r) {
        float a0 = 0.f, a1 = 0.f;
#pragma unroll
        for (int l = 0; l < 8; ++l) {
            a0 = fmaf(u0[l], W[l][r], a0);
            a1 = fmaf(u1[l], W[l][r], a1);
        }
        p000 = fmaf(a0, a0, p000);
        p111 = fmaf(a1, a1, p111);
    }
    {
        float a0 = 0.f, a1 = 0.f;
#pragma unroll
        for (int l = 0; l < 8; ++l) {
            a0 = fmaf(M0[l], z[l], a0);
            a1 = fmaf(M1[l], z[l], a1);
        }
        p000 = fmaf(a0, a0, p000);
        p111 = fmaf(a1, a1, p111);
    }

    if (live) out[e] = (p111 - p000) * 2.0f;
}

extern "C" void kernel_launch(void* const* d_in, const int* in_sizes, int n_in,
                              void* d_out, int out_size, void* d_ws, size_t ws_size,
                              hipStream_t stream) {
    const float* x = (const float*)d_in[0];
    const float* p = (const float*)d_in[1];
    float* out = (float*)d_out;
    int n = in_sizes[0];
    int block = 256;
    int grid = (n + block - 1) / block;   // 1 thread per element; 65536 -> 256 blocks (1/CU)
    pnn_kernel<<<grid, block, 0, stream>>>(x, p, out, n);
}